// Round 1
// baseline (247.413 us; speedup 1.0000x reference)
//
#include <hip/hip_runtime.h>

// Splice kernel: out[m][j] = a[m/R][j]           for j <  sa
//                          = b[m][j - sa]        for sa <= j < sa+sb
//                          = dst[m][j]           for j >= sa+sb
// where sa = seq_len_a[m/R], sb = seq_len_b[m].
// Memory-bound: one thread per int4 (4 consecutive int32s), 2D grid
// (y = row, so sa/sb loads are wave-uniform -> scalarized).

__global__ __launch_bounds__(256) void splice_kernel(
    const int* __restrict__ dst,
    const int* __restrict__ a,
    const int* __restrict__ b,
    const int* __restrict__ seq_a,
    const int* __restrict__ seq_b,
    int* __restrict__ out,
    int LEN_OUT, int LEN_A, int LEN_B, int repeat_shift)
{
    const int m  = blockIdx.y;
    const int vc = blockIdx.x * blockDim.x + threadIdx.x;
    const int nvec = LEN_OUT >> 2;
    if (vc >= nvec) return;

    const int ia    = m >> repeat_shift;
    const int sa    = seq_a[ia];   // block-uniform -> scalar load
    const int sb    = seq_b[m];    // block-uniform -> scalar load
    const int total = sa + sb;
    const int j0    = vc << 2;

    const int* a_row   = a   + (size_t)ia * LEN_A;
    const int* dst_row = dst + (size_t)m  * LEN_OUT;

    int4 v;
    if (j0 + 3 < sa) {
        // fully inside A region: aligned vector load (j0 % 4 == 0, LEN_A % 4 == 0)
        v = *(const int4*)(a_row + j0);
    } else if (j0 >= total) {
        // fully inside pass-through tail: aligned vector load
        v = *(const int4*)(dst_row + j0);
    } else {
        // mixed / B region: at most ~(sb + 8) elements per row -> scalar ok
        const int* b_row = b + (size_t)m * LEN_B;
        int vals[4];
#pragma unroll
        for (int k = 0; k < 4; ++k) {
            const int j = j0 + k;
            int val;
            if (j < sa)         val = a_row[j];
            else if (j < total) val = b_row[j - sa];
            else                val = dst_row[j];
            vals[k] = val;
        }
        v = make_int4(vals[0], vals[1], vals[2], vals[3]);
    }
    *(int4*)(out + (size_t)m * LEN_OUT + j0) = v;
}

extern "C" void kernel_launch(void* const* d_in, const int* in_sizes, int n_in,
                              void* d_out, int out_size, void* d_ws, size_t ws_size,
                              hipStream_t stream) {
    const int* dst   = (const int*)d_in[0];  // (M, LEN_OUT)
    const int* a     = (const int*)d_in[1];  // (BS, LEN_A)
    const int* b     = (const int*)d_in[2];  // (M, LEN_B)
    const int* seq_a = (const int*)d_in[3];  // (BS,)
    const int* seq_b = (const int*)d_in[4];  // (M,)
    int* out = (int*)d_out;

    const int BS      = in_sizes[3];
    const int M       = in_sizes[4];
    const int LEN_A   = in_sizes[1] / BS;
    const int LEN_B   = in_sizes[2] / M;
    const int LEN_OUT = in_sizes[0] / M;
    const int repeat  = M / BS;               // 4
    int repeat_shift = 0;
    while ((1 << repeat_shift) < repeat) ++repeat_shift;

    const int nvec = LEN_OUT / 4;             // 4128
    dim3 block(256);
    dim3 grid((nvec + 255) / 256, M);         // (17, 2048)
    splice_kernel<<<grid, block, 0, stream>>>(dst, a, b, seq_a, seq_b, out,
                                              LEN_OUT, LEN_A, LEN_B, repeat_shift);
}